// Round 4
// baseline (295.819 us; speedup 1.0000x reference)
//
#include <hip/hip_runtime.h>

// ---------------------------------------------------------------------------
// CAPA_62886911148616: windowed local attention, SC=11, c=64, b=2, 256x256.
// R10: attn waves = query-QUARTER x all keys. Each wave owns 32 queries and
// iterates all key quarter-tiles (unit = 32 keys), so per-wave O/lsum are
// complete: NO LDS, NO barriers, NO merge. 2-buffer register prefetch,
// __launch_bounds__(256,3) pins ~168 VGPR -> 3 waves/SIMD self-paced.
// (R9 evidence: self-pacing doubled per-wave duty but 244 VGPR halved
// occupancy; this keeps the duty and restores the waves.)
// R8: native __bf16 casts. Proj/ep unchanged (R4-proven).
// MFMA f32_16x16x32_bf16: A m=lane&15,k=8h+j; B n=lane&15,k=8h+j;
// C/D col=lane&15, row=4h+reg.
// ---------------------------------------------------------------------------

typedef unsigned short ushort_t;
typedef unsigned int   uint32;
typedef unsigned long long uint64;
typedef __attribute__((ext_vector_type(8))) short short8;   // 8 x bf16 bits
typedef __attribute__((ext_vector_type(4))) float f32x4;

#define MFMA16(a,b,c) __builtin_amdgcn_mfma_f32_16x16x32_bf16(a,b,c,0,0,0)

#if __has_builtin(__builtin_amdgcn_exp2f)
#define EXP2(x) __builtin_amdgcn_exp2f(x)
#else
#define EXP2(x) exp2f(x)
#endif
#if __has_builtin(__builtin_amdgcn_rcpf)
#define RCP(x) __builtin_amdgcn_rcpf(x)
#else
#define RCP(x) (1.0f/(x))
#endif

// ws layout (bytes): Q | K | V packets, each 1152 tiles * 16KB = 56.6 MiB.
// rbuf (bf16 [win][q128][ch64]) overlays qpkt (each attn wave reads its own
// query quarter fully before writing the same region).
#define QPKT_OFF   0u
#define KPKT_OFF   18874368u
#define VPKT_OFF   37748736u

// f32 -> bf16 via native cast (fptrunc, RNE). Backend emits hardware cvt;
// paired uses get fused into v_cvt_pk_bf16_f32.
__device__ __forceinline__ ushort_t f2bf(float f){
  union { __bf16 h; ushort_t u; } c;
  c.h = (__bf16)f;
  return c.u;
}

__device__ __forceinline__ uint32 pkbf(float a, float b){
  union { __bf16 h[2]; uint32 u; } c;
  c.h[0] = (__bf16)a;
  c.h[1] = (__bf16)b;
  return c.u;
}

// store one D[ch][pix] C-frag into K/Q packet layout (8 bytes, R2-verified)
__device__ __forceinline__ void storeK8(ushort_t* __restrict__ base, int nt, int t,
                                        int l15, int h, f32x4 a){
  uint32 lo = pkbf(a[0], a[1]);
  uint32 hi = pkbf(a[2], a[3]);
  int lanep = l15 + 16*((2*t + (h>>1)) & 3);
  size_t off = (size_t)((nt*2 + (t>>1))*64 + lanep)*16 + 8*(h&1);
  *(uint2*)((char*)base + off) = make_uint2(lo, hi);
}

__device__ __forceinline__ short8 ldWfrag(const float* __restrict__ W, int t, int ks,
                                          int l15, int h, float scale){
  const float* p = W + (16*t + l15)*64 + 32*ks + 8*h;
  float4 a = *(const float4*)p;
  float4 b = *(const float4*)(p + 4);
  union { uint4 u; short8 s; } x;
  x.u.x = pkbf(a.x*scale, a.y*scale);
  x.u.y = pkbf(a.z*scale, a.w*scale);
  x.u.z = pkbf(b.x*scale, b.y*scale);
  x.u.w = pkbf(b.z*scale, b.w*scale);
  return x.s;
}

// ---------------------------------------------------------------------------
// Kernel 1: projections (R4-proven structure; R8 conversion fix).
// ---------------------------------------------------------------------------
__global__ __launch_bounds__(256) void proj_kernel(
    const float* __restrict__ xk, const float* __restrict__ xr,
    const float* __restrict__ Wq, const float* __restrict__ Wk, const float* __restrict__ Wv,
    ushort_t* __restrict__ qpkt, ushort_t* __restrict__ kpkt, ushort_t* __restrict__ vpkt)
{
  __shared__ __align__(16) float sX[64*192];
  const int tid = threadIdx.x;
  const int lane = tid & 63, wv = tid >> 6;
  const int l15 = lane & 15, h = lane >> 4;
  const int bid = blockIdx.x;
  const bool isQ = bid >= 1152;
  const int id = isQ ? bid - 1152 : bid;
  const int b = id / 576, rem = id % 576, ty = rem / 24, tx = rem % 24;
  const float* xs = (isQ ? xk : xr) + (size_t)b*64*65536;
  const int oy = ty*11, ox = tx*11;
  const int ox3 = ox & 3, xa = ox - ox3;

  #pragma unroll
  for (int i = tid; i < 1024; i += 256) sX[(i>>4)*192 + 176 + (i&15)] = 0.f;

  {
    const int ch = tid >> 2, seg = tid & 3;
    const float* rowp = xs + (size_t)ch*65536 + (size_t)oy*256 + (xa + 4*seg);
    float* sdst = sX + ch*192 + 4*seg;
    if (ty < 23 && tx < 23){
      #pragma unroll
      for (int y = 0; y < 11; ++y)
        *(float4*)(sdst + y*16) = *(const float4*)(rowp + y*256);
    } else {
      const int xg = xa + 4*seg;
      #pragma unroll
      for (int y = 0; y < 11; ++y){
        const bool rk = (oy + y) < 256;
        float4 v;
        v.x = (rk && xg+0 < 256) ? rowp[y*256+0] : 0.f;
        v.y = (rk && xg+1 < 256) ? rowp[y*256+1] : 0.f;
        v.z = (rk && xg+2 < 256) ? rowp[y*256+2] : 0.f;
        v.w = (rk && xg+3 < 256) ? rowp[y*256+3] : 0.f;
        *(float4*)(sdst + y*16) = v;
      }
    }
  }
  __syncthreads();

  const f32x4 zero = {0.f, 0.f, 0.f, 0.f};
  #define XFL(nt, ks, dst) { \
    const int px_ = 16*(nt) + l15; \
    const int y_ = (px_*745) >> 13; \
    const float* pp_ = sX + (32*(ks) + 8*h)*192 + y_*16 + (px_ - y_*11) + ox3; \
    union { uint4 u; short8 s; } r_; \
    r_.u.x = pkbf(pp_[0],    pp_[192]); \
    r_.u.y = pkbf(pp_[384],  pp_[576]); \
    r_.u.z = pkbf(pp_[768],  pp_[960]); \
    r_.u.w = pkbf(pp_[1152], pp_[1344]); \
    dst = r_.s; }

  if (!isQ){
    short8 wkf[4][2], wvf[4][2];
    #pragma unroll
    for (int t = 0; t < 4; ++t){
      wkf[t][0] = ldWfrag(Wk, t, 0, l15, h, 1.f);  wkf[t][1] = ldWfrag(Wk, t, 1, l15, h, 1.f);
      wvf[t][0] = ldWfrag(Wv, t, 0, l15, h, 1.f);  wvf[t][1] = ldWfrag(Wv, t, 1, l15, h, 1.f);
    }
    ushort_t* kb = kpkt + (size_t)id*8192;
    ushort_t* vb = vpkt + (size_t)id*8192;
    const int nt0 = 2*wv, nt1 = 2*wv + 1;
    short8 xf0[2], xf1[2];
    XFL(nt0, 0, xf0[0]); XFL(nt0, 1, xf0[1]);
    XFL(nt1, 0, xf1[0]); XFL(nt1, 1, xf1[1]);
    #pragma unroll
    for (int t = 0; t < 4; ++t){
      f32x4 ak0 = MFMA16(wkf[t][0], xf0[0], zero); ak0 = MFMA16(wkf[t][1], xf0[1], ak0);
      f32x4 ak1 = MFMA16(wkf[t][0], xf1[0], zero); ak1 = MFMA16(wkf[t][1], xf1[1], ak1);
      f32x4 av0 = MFMA16(xf0[0], wvf[t][0], zero); av0 = MFMA16(xf0[1], wvf[t][1], av0);
      f32x4 av1 = MFMA16(xf1[0], wvf[t][0], zero); av1 = MFMA16(xf1[1], wvf[t][1], av1);
      storeK8(kb, nt0, t, l15, h, ak0);
      storeK8(kb, nt1, t, l15, h, ak1);
      uint4 pv;
      pv.x = pkbf(av0[0], av0[1]); pv.y = pkbf(av0[2], av0[3]);
      pv.z = pkbf(av1[0], av1[1]); pv.w = pkbf(av1[2], av1[3]);
      *(uint4*)((char*)vb + (size_t)((wv*4 + t)*64 + lane)*16) = pv;
    }
  } else {
    const float C1 = 0.18033688011112042f;   // (1/8)/ln2 folded into Q
    short8 wqf[4][2];
    #pragma unroll
    for (int t = 0; t < 4; ++t){
      wqf[t][0] = ldWfrag(Wq, t, 0, l15, h, C1);  wqf[t][1] = ldWfrag(Wq, t, 1, l15, h, C1);
    }
    ushort_t* qb = qpkt + (size_t)id*8192;
    #pragma unroll
    for (int nn = 0; nn < 2; ++nn){
      const int nt = 2*wv + nn;
      short8 xf[2];
      XFL(nt, 0, xf[0]); XFL(nt, 1, xf[1]);
      #pragma unroll
      for (int t = 0; t < 4; ++t){
        f32x4 aq = MFMA16(wqf[t][0], xf[0], zero); aq = MFMA16(wqf[t][1], xf[1], aq);
        storeK8(qb, nt, t, l15, h, aq);
      }
    }
  }
  #undef XFL
}

// ---------------------------------------------------------------------------
// Kernel 2: attention. 256 thr = 4 waves = 1 window; wave qq = query quarter
// (32 queries), iterating ALL key quarter-tiles. Unit = (tile, qtr) = 32 keys.
// Per-wave complete O/lsum: no LDS, no barriers, no merge. 2-buffer register
// prefetch (distance 1 unit), compiler-counted vmcnt; setprio around MFMA.
// qtr plays the old ntp role exactly: K/V offset qtr*4096, bias kl formula
// unchanged, interior pad-bias when qtr==3,kt==1. Alias-safe: each wave reads
// Q region [win*8192 + qq*2048, +2048) fully before writing the same region.
// ---------------------------------------------------------------------------
__global__ __launch_bounds__(256, 3) void attn_kernel(
    ushort_t* qpkt,                      // aliases rbuf! no __restrict__
    const ushort_t* __restrict__ kpkt, const ushort_t* __restrict__ vpkt,
    const float* __restrict__ gamma)
{
  const int tid = threadIdx.x;
  const int lane = tid & 63, qq = tid >> 6;
  const int win = (blockIdx.x & 7)*144 + (blockIdx.x >> 3);   // XCD swizzle
  const int b = win / 576, wid = win % 576, wy = wid / 24, wx = wid % 24;
  const int l15 = lane & 15, h = lane >> 4;

  // resident Q A-frags for this wave's query quarter (nt groups 2qq, 2qq+1)
  short8 qf[2][2];
  {
    const ushort_t* qblk = qpkt + (size_t)win*8192;
    #pragma unroll
    for (int mt = 0; mt < 2; ++mt){
      qf[mt][0] = *(const short8*)(qblk + (size_t)(((2*qq+mt)*2 + 0)*64 + lane)*8);
      qf[mt][1] = *(const short8*)(qblk + (size_t)(((2*qq+mt)*2 + 1)*64 + lane)*8);
    }
  }

  // valid-tile nibble list
  uint64 cks = 0; int nv = 0;
  #pragma unroll
  for (int ck = 0; ck < 9; ++ck){
    const int ty = wy - 1 + ck/3, tx = wx - 1 + ck%3;
    if ((unsigned)ty < 24u && (unsigned)tx < 24u){
      cks |= ((uint64)ck) << (4*nv); ++nv;
    }
  }
  const int nu = 4*nv;   // quarter-tile units; nv>=4 so nu>=16

  const f32x4 zz = {0.f,0.f,0.f,0.f};
  f32x4 o[2][4], lsumC[2];
  #pragma unroll
  for (int mt = 0; mt < 2; ++mt){
    lsumC[mt] = zz;
    #pragma unroll
    for (int u = 0; u < 4; ++u) o[mt][u] = zz;
  }
  // interior bias for qtr==3,kt==1: key 112+4h+r invalid iff 4h+r>=9
  f32x4 init_i;
  #pragma unroll
  for (int r = 0; r < 4; ++r) init_i[r] = (4*h + r >= 9) ? -1.0e4f : 0.f;
  // ones B-frag for denominator MFMA
  short8 ones;
  #pragma unroll
  for (int j = 0; j < 8; ++j) ones[j] = (short)0x3F80;

  const int lane16 = lane*16;

  // issue 8 direct global->VGPR frag loads for unit u_ (K r0..3, V r0..3)
  #define ISSUE(KD, VD, u_) { \
    const int t_ = (u_) >> 2, qtr_ = (u_) & 3; \
    const int ck_ = (int)((cks >> (4*t_)) & 15); \
    const int cy_ = (ck_*11) >> 5; \
    const size_t tb_ = ((size_t)(b*576 + (wy-1+cy_)*24 + (wx-1+(ck_-3*cy_))) << 14) \
                       + ((size_t)qtr_ << 12) + (size_t)lane16; \
    const char* kg_ = (const char*)kpkt + tb_; \
    const char* vg_ = (const char*)vpkt + tb_; \
    _Pragma("unroll") \
    for (int r_ = 0; r_ < 4; ++r_){ \
      KD[r_] = *(const short8*)(kg_ + r_*1024); \
      VD[r_] = *(const short8*)(vg_ + r_*1024); \
    } }

  #define COMPUTE(KC, VC, u_) { \
    const int t_ = (u_) >> 2, qtr_ = (u_) & 3; \
    const int ckv = (int)((cks >> (4*t_)) & 15); \
    const int cyv = (ckv*11) >> 5; \
    const int tyv = wy - 1 + cyv, txv = wx - 1 + (ckv - 3*cyv); \
    const bool ey = (tyv == 23), ex = (txv == 23); \
    f32x4 b0, b1; \
    if (ey | ex){ \
      _Pragma("unroll") \
      for (int kt = 0; kt < 2; ++kt){ \
        f32x4 bb; \
        _Pragma("unroll") \
        for (int r = 0; r < 4; ++r){ \
          const int kl = 32*qtr_ + 16*kt + 4*h + r; \
          const int ky = (kl*745) >> 13, kx = kl - ky*11; \
          bool ok = (kl < 121) && (!ey || ky < 3) && (!ex || kx < 3); \
          bb[r] = ok ? 0.f : -1.0e4f; \
        } \
        if (kt) b1 = bb; else b0 = bb; \
      } \
    } else { \
      b0 = zz; \
      b1 = (qtr_ == 3) ? init_i : zz;   /* interior pad keys */ \
    } \
    __builtin_amdgcn_s_setprio(1); \
    _Pragma("unroll") \
    for (int mt = 0; mt < 2; ++mt){ \
      f32x4 s0 = MFMA16(KC[0], qf[mt][0], b0); s0 = MFMA16(KC[1], qf[mt][1], s0); \
      f32x4 s1 = MFMA16(KC[2], qf[mt][0], b1); s1 = MFMA16(KC[3], qf[mt][1], s1); \
      float p[8]; \
      _Pragma("unroll") \
      for (int r = 0; r < 4; ++r){ \
        p[r]   = EXP2(s0[r]); \
        p[4+r] = EXP2(s1[r]); \
      } \
      union { uint4 uu; short8 s; } af; \
      af.uu.x = pkbf(p[0], p[1]); af.uu.y = pkbf(p[2], p[3]); \
      af.uu.z = pkbf(p[4], p[5]); af.uu.w = pkbf(p[6], p[7]); \
      o[mt][0] = MFMA16(af.s, VC[0], o[mt][0]); \
      o[mt][1] = MFMA16(af.s, VC[1], o[mt][1]); \
      o[mt][2] = MFMA16(af.s, VC[2], o[mt][2]); \
      o[mt][3] = MFMA16(af.s, VC[3], o[mt][3]); \
      lsumC[mt] = MFMA16(af.s, ones, lsumC[mt]); \
    } \
    __builtin_amdgcn_s_setprio(0); }

  // double-buffered register frags (constant-indexed -> stay in VGPRs)
  short8 kA[4], vA[4], kB[4], vB[4];

  ISSUE(kA, vA, 0);
  ISSUE(kB, vB, 1);

  {
    int u = 0;
    #pragma unroll 1
    while (true){
      COMPUTE(kA, vA, u); if (u + 2 < nu) ISSUE(kA, vA, u + 2);
      if (++u >= nu) break;
      COMPUTE(kB, vB, u); if (u + 2 < nu) ISSUE(kB, vB, u + 2);
      if (++u >= nu) break;
    }
  }
  #undef ISSUE
  #undef COMPUTE

  // ---- epilogue: normalize + store bf16 r into this wave's Q region ----
  const float gm = gamma[0];
  ushort_t* rb = qpkt + (size_t)win*8192;
  #pragma unroll
  for (int mt = 0; mt < 2; ++mt){
    #pragma unroll
    for (int r = 0; r < 4; ++r){
      const float wg = gm * RCP(lsumC[mt][r]);   // den per-lane (C-layout)
      const int qs = 32*qq + 16*mt + 4*h + r;
      #pragma unroll
      for (int u = 0; u < 4; ++u)
        rb[(size_t)qs*64 + 16*u + l15] = f2bf(wg * o[mt][u][r]);
    }
  }
}

// ---------------------------------------------------------------------------
// Kernel 3: out = xref + r. LDS-tiled, both sides coalesced (R4-proven).
// ---------------------------------------------------------------------------
__global__ __launch_bounds__(256) void ep_kernel(
    const float* __restrict__ xref, const ushort_t* __restrict__ rbuf,
    float* __restrict__ out)
{
  __shared__ float tile[64][65];
  const int tid = threadIdx.x;
  const int bidx = blockIdx.x;                 // 2048 = b(2) x y(256) x xc(4)
  const int xc = bidx & 3, y = (bidx >> 2) & 255, b = bidx >> 10;
  const int wy = (y*745) >> 13, qy = y - wy*11;
  {
    const int ch = tid & 63, xs4 = tid >> 6;
    #pragma unroll
    for (int xi = 0; xi < 16; ++xi){
      const int xl = xi*4 + xs4;
      const int x = xc*64 + xl;
      const int wx = (x*745) >> 13, qx = x - wx*11;
      const size_t ridx = (size_t)(b*576 + wy*24 + wx)*8192 + (size_t)(qy*11 + qx)*64 + ch;
      tile[xl][ch] = __uint_as_float(((uint32)rbuf[ridx]) << 16);
    }
  }
  __syncthreads();
  {
    const int xl = tid & 63, cg = tid >> 6;
    const size_t base = (size_t)b*4194304 + (size_t)y*256 + xc*64 + xl;
    #pragma unroll
    for (int ci = 0; ci < 16; ++ci){
      const int c2 = ci*4 + cg;
      const size_t idx = base + (size_t)c2*65536;
      out[idx] = xref[idx] + tile[xl][c2];
    }
  }
}

// ---------------------------------------------------------------------------
extern "C" void kernel_launch(void* const* d_in, const int* in_sizes, int n_in,
                              void* d_out, int out_size, void* d_ws, size_t ws_size,
                              hipStream_t stream)
{
  const float* xk = (const float*)d_in[0];
  const float* xr = (const float*)d_in[1];
  const float* Wq = (const float*)d_in[2];
  const float* Wk = (const float*)d_in[3];
  const float* Wv = (const float*)d_in[4];
  const float* gm = (const float*)d_in[5];
  float* out = (float*)d_out;
  char* ws = (char*)d_ws;
  ushort_t* qp = (ushort_t*)(ws + QPKT_OFF);   // rbuf overlays this region
  ushort_t* kp = (ushort_t*)(ws + KPKT_OFF);
  ushort_t* vp = (ushort_t*)(ws + VPKT_OFF);
  (void)in_sizes; (void)n_in; (void)out_size; (void)ws_size;  // needs 56.6 MiB

  proj_kernel<<<2304, 256, 0, stream>>>(xk, xr, Wq, Wk, Wv, qp, kp, vp);
  attn_kernel<<<1152, 256, 0, stream>>>(qp, kp, vp, gm);
  ep_kernel<<<2048, 256, 0, stream>>>(xr, qp, out);
}

// Round 5
// 232.518 us; speedup vs baseline: 1.2722x; 1.2722x over previous
//
#include <hip/hip_runtime.h>

// ---------------------------------------------------------------------------
// CAPA_62886911148616: windowed local attention, SC=11, c=64, b=2, 256x256.
// R11: single barrier per unit. With the 3-buffer rotation, the closing
// barrier is redundant: a wave passing the OPENING barrier of unit u+1 has
// necessarily completed its unit-u ds_reads (compiler lgkmcnt waits precede
// the consuming MFMAs), so the buffer restaged right after that barrier
// (buf (u+3)%3 = u%3) is provably drained. Barriers/window: 34 -> 17.
// Everything else identical to R8 (87us attn): 3-buffer LDS staging via
// global_load_lds, counted vmcnt(4) never drained mid-loop, prefetch
// distance 2 units, setprio around MFMA cluster, bias-init masking,
// ones-MFMA denominator, LDS O-merge. R9/R10 showed self-paced variants
// lose to VGPR pressure/spills; this keeps VGPR ~104.
// MFMA f32_16x16x32_bf16: A m=lane&15,k=8h+j; B n=lane&15,k=8h+j;
// C/D col=lane&15, row=4h+reg.
// ---------------------------------------------------------------------------

typedef unsigned short ushort_t;
typedef unsigned int   uint32;
typedef unsigned long long uint64;
typedef __attribute__((ext_vector_type(8))) short short8;   // 8 x bf16 bits
typedef __attribute__((ext_vector_type(4))) float f32x4;

#define MFMA16(a,b,c) __builtin_amdgcn_mfma_f32_16x16x32_bf16(a,b,c,0,0,0)

#if __has_builtin(__builtin_amdgcn_exp2f)
#define EXP2(x) __builtin_amdgcn_exp2f(x)
#else
#define EXP2(x) exp2f(x)
#endif
#if __has_builtin(__builtin_amdgcn_rcpf)
#define RCP(x) __builtin_amdgcn_rcpf(x)
#else
#define RCP(x) (1.0f/(x))
#endif

// ws layout (bytes): Q | K | V packets, each 1152 tiles * 16KB = 56.6 MiB.
// rbuf (bf16 [win][q128][ch64]) overlays qpkt (each attn block reads its own
// window's 16KB fully before writing it).
#define QPKT_OFF   0u
#define KPKT_OFF   18874368u
#define VPKT_OFF   37748736u

// f32 -> bf16 via native cast (fptrunc, RNE). Backend emits hardware cvt;
// paired uses get fused into v_cvt_pk_bf16_f32.
__device__ __forceinline__ ushort_t f2bf(float f){
  union { __bf16 h; ushort_t u; } c;
  c.h = (__bf16)f;
  return c.u;
}

__device__ __forceinline__ uint32 pkbf(float a, float b){
  union { __bf16 h[2]; uint32 u; } c;
  c.h[0] = (__bf16)a;
  c.h[1] = (__bf16)b;
  return c.u;
}

// store one D[ch][pix] C-frag into K/Q packet layout (8 bytes, R2-verified)
__device__ __forceinline__ void storeK8(ushort_t* __restrict__ base, int nt, int t,
                                        int l15, int h, f32x4 a){
  uint32 lo = pkbf(a[0], a[1]);
  uint32 hi = pkbf(a[2], a[3]);
  int lanep = l15 + 16*((2*t + (h>>1)) & 3);
  size_t off = (size_t)((nt*2 + (t>>1))*64 + lanep)*16 + 8*(h&1);
  *(uint2*)((char*)base + off) = make_uint2(lo, hi);
}

__device__ __forceinline__ short8 ldWfrag(const float* __restrict__ W, int t, int ks,
                                          int l15, int h, float scale){
  const float* p = W + (16*t + l15)*64 + 32*ks + 8*h;
  float4 a = *(const float4*)p;
  float4 b = *(const float4*)(p + 4);
  union { uint4 u; short8 s; } x;
  x.u.x = pkbf(a.x*scale, a.y*scale);
  x.u.y = pkbf(a.z*scale, a.w*scale);
  x.u.z = pkbf(b.x*scale, b.y*scale);
  x.u.w = pkbf(b.z*scale, b.w*scale);
  return x.s;
}

// ---------------------------------------------------------------------------
// Kernel 1: projections (R4-proven structure; R8 conversion fix).
// ---------------------------------------------------------------------------
__global__ __launch_bounds__(256) void proj_kernel(
    const float* __restrict__ xk, const float* __restrict__ xr,
    const float* __restrict__ Wq, const float* __restrict__ Wk, const float* __restrict__ Wv,
    ushort_t* __restrict__ qpkt, ushort_t* __restrict__ kpkt, ushort_t* __restrict__ vpkt)
{
  __shared__ __align__(16) float sX[64*192];
  const int tid = threadIdx.x;
  const int lane = tid & 63, wv = tid >> 6;
  const int l15 = lane & 15, h = lane >> 4;
  const int bid = blockIdx.x;
  const bool isQ = bid >= 1152;
  const int id = isQ ? bid - 1152 : bid;
  const int b = id / 576, rem = id % 576, ty = rem / 24, tx = rem % 24;
  const float* xs = (isQ ? xk : xr) + (size_t)b*64*65536;
  const int oy = ty*11, ox = tx*11;
  const int ox3 = ox & 3, xa = ox - ox3;

  #pragma unroll
  for (int i = tid; i < 1024; i += 256) sX[(i>>4)*192 + 176 + (i&15)] = 0.f;

  {
    const int ch = tid >> 2, seg = tid & 3;
    const float* rowp = xs + (size_t)ch*65536 + (size_t)oy*256 + (xa + 4*seg);
    float* sdst = sX + ch*192 + 4*seg;
    if (ty < 23 && tx < 23){
      #pragma unroll
      for (int y = 0; y < 11; ++y)
        *(float4*)(sdst + y*16) = *(const float4*)(rowp + y*256);
    } else {
      const int xg = xa + 4*seg;
      #pragma unroll
      for (int y = 0; y < 11; ++y){
        const bool rk = (oy + y) < 256;
        float4 v;
        v.x = (rk && xg+0 < 256) ? rowp[y*256+0] : 0.f;
        v.y = (rk && xg+1 < 256) ? rowp[y*256+1] : 0.f;
        v.z = (rk && xg+2 < 256) ? rowp[y*256+2] : 0.f;
        v.w = (rk && xg+3 < 256) ? rowp[y*256+3] : 0.f;
        *(float4*)(sdst + y*16) = v;
      }
    }
  }
  __syncthreads();

  const f32x4 zero = {0.f, 0.f, 0.f, 0.f};
  #define XFL(nt, ks, dst) { \
    const int px_ = 16*(nt) + l15; \
    const int y_ = (px_*745) >> 13; \
    const float* pp_ = sX + (32*(ks) + 8*h)*192 + y_*16 + (px_ - y_*11) + ox3; \
    union { uint4 u; short8 s; } r_; \
    r_.u.x = pkbf(pp_[0],    pp_[192]); \
    r_.u.y = pkbf(pp_[384],  pp_[576]); \
    r_.u.z = pkbf(pp_[768],  pp_[960]); \
    r_.u.w = pkbf(pp_[1152], pp_[1344]); \
    dst = r_.s; }

  if (!isQ){
    short8 wkf[4][2], wvf[4][2];
    #pragma unroll
    for (int t = 0; t < 4; ++t){
      wkf[t][0] = ldWfrag(Wk, t, 0, l15, h, 1.f);  wkf[t][1] = ldWfrag(Wk, t, 1, l15, h, 1.f);
      wvf[t][0] = ldWfrag(Wv, t, 0, l15, h, 1.f);  wvf[t][1] = ldWfrag(Wv, t, 1, l15, h, 1.f);
    }
    ushort_t* kb = kpkt + (size_t)id*8192;
    ushort_t* vb = vpkt + (size_t)id*8192;
    const int nt0 = 2*wv, nt1 = 2*wv + 1;
    short8 xf0[2], xf1[2];
    XFL(nt0, 0, xf0[0]); XFL(nt0, 1, xf0[1]);
    XFL(nt1, 0, xf1[0]); XFL(nt1, 1, xf1[1]);
    #pragma unroll
    for (int t = 0; t < 4; ++t){
      f32x4 ak0 = MFMA16(wkf[t][0], xf0[0], zero); ak0 = MFMA16(wkf[t][1], xf0[1], ak0);
      f32x4 ak1 = MFMA16(wkf[t][0], xf1[0], zero); ak1 = MFMA16(wkf[t][1], xf1[1], ak1);
      f32x4 av0 = MFMA16(xf0[0], wvf[t][0], zero); av0 = MFMA16(xf0[1], wvf[t][1], av0);
      f32x4 av1 = MFMA16(xf1[0], wvf[t][0], zero); av1 = MFMA16(xf1[1], wvf[t][1], av1);
      storeK8(kb, nt0, t, l15, h, ak0);
      storeK8(kb, nt1, t, l15, h, ak1);
      uint4 pv;
      pv.x = pkbf(av0[0], av0[1]); pv.y = pkbf(av0[2], av0[3]);
      pv.z = pkbf(av1[0], av1[1]); pv.w = pkbf(av1[2], av1[3]);
      *(uint4*)((char*)vb + (size_t)((wv*4 + t)*64 + lane)*16) = pv;
    }
  } else {
    const float C1 = 0.18033688011112042f;   // (1/8)/ln2 folded into Q
    short8 wqf[4][2];
    #pragma unroll
    for (int t = 0; t < 4; ++t){
      wqf[t][0] = ldWfrag(Wq, t, 0, l15, h, C1);  wqf[t][1] = ldWfrag(Wq, t, 1, l15, h, C1);
    }
    ushort_t* qb = qpkt + (size_t)id*8192;
    #pragma unroll
    for (int nn = 0; nn < 2; ++nn){
      const int nt = 2*wv + nn;
      short8 xf[2];
      XFL(nt, 0, xf[0]); XFL(nt, 1, xf[1]);
      #pragma unroll
      for (int t = 0; t < 4; ++t){
        f32x4 aq = MFMA16(wqf[t][0], xf[0], zero); aq = MFMA16(wqf[t][1], xf[1], aq);
        storeK8(qb, nt, t, l15, h, aq);
      }
    }
  }
  #undef XFL
}

// ---------------------------------------------------------------------------
// Kernel 2: attention. 256 thr = 4 waves = 1 window; wave = (qh, kh).
// Unit = tile-half (8KB K + 8KB V); each wave stages a 4KB quarter and
// computes its kh's 32 keys for its qh's 64 queries. Bias-init masking,
// ones-MFMA denominator, LDS O-merge, epilogue by kh==0 waves.
// R11: ONE barrier per unit (see file header). 3-buffer rotation; STAGE for
// u+2 issued right after the barrier (it overwrites buf (u+2)%3 = (u-1)%3,
// drained by this same barrier). Counted vmcnt(4) mid-loop, vmcnt(0) tail.
// ---------------------------------------------------------------------------
__global__ __launch_bounds__(256) void attn_kernel(
    ushort_t* qpkt,                      // aliases rbuf! no __restrict__
    const ushort_t* __restrict__ kpkt, const ushort_t* __restrict__ vpkt,
    const float* __restrict__ gamma)
{
  __shared__ __align__(16) char smem[49152];
  const int tid = threadIdx.x;
  const int lane = tid & 63, wave = tid >> 6;
  const int qh = wave & 1, kh = wave >> 1;
  const int win = (blockIdx.x & 7)*144 + (blockIdx.x >> 3);   // XCD swizzle
  const int b = win / 576, wid = win % 576, wy = wid / 24, wx = wid % 24;
  const int l15 = lane & 15, h = lane >> 4;

  // resident Q A-frags for this wave's query half
  short8 qf[4][2];
  {
    const ushort_t* qblk = qpkt + (size_t)win*8192;
    #pragma unroll
    for (int mt = 0; mt < 4; ++mt){
      qf[mt][0] = *(const short8*)(qblk + (size_t)(((4*qh+mt)*2 + 0)*64 + lane)*8);
      qf[mt][1] = *(const short8*)(qblk + (size_t)(((4*qh+mt)*2 + 1)*64 + lane)*8);
    }
  }

  // valid-tile nibble list
  uint64 cks = 0; int nv = 0;
  #pragma unroll
  for (int ck = 0; ck < 9; ++ck){
    const int ty = wy - 1 + ck/3, tx = wx - 1 + ck%3;
    if ((unsigned)ty < 24u && (unsigned)tx < 24u){
      cks |= ((uint64)ck) << (4*nv); ++nv;
    }
  }
  const int nu = 2*nv;   // units; nv>=4 so nu>=8

  const f32x4 zz = {0.f,0.f,0.f,0.f};
  f32x4 o[4][4], lsumC[4];
  #pragma unroll
  for (int mt = 0; mt < 4; ++mt){
    lsumC[mt] = zz;
    #pragma unroll
    for (int u = 0; u < 4; ++u) o[mt][u] = zz;
  }
  // interior bias for ntp==3,kt==1: key 112+4h+r invalid iff 4h+r>=9
  f32x4 init_i;
  #pragma unroll
  for (int r = 0; r < 4; ++r) init_i[r] = (4*h + r >= 9) ? -1.0e4f : 0.f;
  // ones B-frag for denominator MFMA
  short8 ones;
  #pragma unroll
  for (int j = 0; j < 8; ++j) ones[j] = (short)0x3F80;

  const ushort_t* gsrc = (wave < 2) ? kpkt : vpkt;
  const int ldsoff = (wave >> 1)*8192 + (wave & 1)*4096;

  #define STAGE(u, bo) { \
    const int t_ = (u) >> 1, hf_ = (u) & 1; \
    const int ck_ = (int)((cks >> (4*t_)) & 15); \
    const int cy_ = (ck_*11) >> 5; \
    const int ty_ = wy - 1 + cy_, tx_ = wx - 1 + (ck_ - 3*cy_); \
    const char* g_ = (const char*)(gsrc + (size_t)(b*576 + ty_*24 + tx_)*8192) \
                     + hf_*8192 + (wave & 1)*4096 + lane*16; \
    char* l_ = smem + (bo)*16384 + ldsoff + lane*16; \
    _Pragma("unroll") \
    for (int i_ = 0; i_ < 4; ++i_) \
      __builtin_amdgcn_global_load_lds( \
        (const __attribute__((address_space(1))) uint32*)(g_ + i_*1024), \
        (__attribute__((address_space(3))) uint32*)(l_ + i_*1024), 16, 0, 0); \
  }

  // prologue: stage units 0,1 into buffers 0,1 (prefetch distance 2)
  STAGE(0, 0);
  STAGE(1, 1);

  int bu = 0;   // rotating buffer index = u % 3
  #pragma unroll 1
  for (int u = 0; u < nu; ++u){
    // own stage(u) must be done; stage(u+1) may remain in flight
    if (u + 1 < nu) { __asm__ volatile("s_waitcnt vmcnt(4)" ::: "memory"); }
    else            { __asm__ volatile("s_waitcnt vmcnt(0)" ::: "memory"); }
    __builtin_amdgcn_s_barrier();        // ALL waves' stage(u) landed; ALL
                                         // waves' reads of buf (u-1)%3 done
    __asm__ volatile("" ::: "memory");

    const int bn = (bu == 2) ? 0 : bu + 1;      // (u+1)%3
    const int b2 = (bn == 2) ? 0 : bn + 1;      // (u+2)%3 — drained buffer
    if (u + 2 < nu) STAGE(u + 2, b2);

    const int t = u >> 1, hf = u & 1;
    const int ckv = (int)((cks >> (4*t)) & 15);
    const int cyv = (ckv*11) >> 5;
    const int tyv = wy - 1 + cyv, txv = wx - 1 + (ckv - 3*cyv);
    const bool ey = (tyv == 23), ex = (txv == 23);
    const int ntp = 2*hf + kh;

    // S-MFMA accumulator-init bias (masking); wave-uniform branch
    f32x4 b0, b1;
    if (ey | ex){
      #pragma unroll
      for (int kt = 0; kt < 2; ++kt){
        f32x4 bb;
        #pragma unroll
        for (int r = 0; r < 4; ++r){
          const int kl = 32*ntp + 16*kt + 4*h + r;
          const int ky = (kl*745) >> 13, kx = kl - ky*11;
          bool ok = (kl < 121) && (!ey || ky < 3) && (!ex || kx < 3);
          bb[r] = ok ? 0.f : -1.0e4f;
        }
        if (kt) b1 = bb; else b0 = bb;
      }
    } else {
      b0 = zz;
      b1 = (hf & kh) ? init_i : zz;   // ntp==3, kt==1 pad keys
    }

    const char* lk = smem + bu*16384 + kh*4096;
    const char* lv = smem + bu*16384 + 8192 + kh*4096;
    short8 kf00 = *(const short8*)(lk + (0*64 + lane)*16);
    short8 kf01 = *(const short8*)(lk + (1*64 + lane)*16);
    short8 kf10 = *(const short8*)(lk + (2*64 + lane)*16);
    short8 kf11 = *(const short8*)(lk + (3*64 + lane)*16);
    short8 vf0  = *(const short8*)(lv + (0*64 + lane)*16);
    short8 vf1  = *(const short8*)(lv + (1*64 + lane)*16);
    short8 vf2  = *(const short8*)(lv + (2*64 + lane)*16);
    short8 vf3  = *(const short8*)(lv + (3*64 + lane)*16);

    __builtin_amdgcn_s_setprio(1);
    #pragma unroll
    for (int mt = 0; mt < 4; ++mt){
      f32x4 s0 = MFMA16(kf00, qf[mt][0], b0); s0 = MFMA16(kf01, qf[mt][1], s0);
      f32x4 s1 = MFMA16(kf10, qf[mt][0], b1); s1 = MFMA16(kf11, qf[mt][1], s1);
      float p[8];
      #pragma unroll
      for (int r = 0; r < 4; ++r){
        p[r]   = EXP2(s0[r]);   // Q pre-scaled; invalid keys carry -1e4 bias -> 0
        p[4+r] = EXP2(s1[r]);
      }
      union { uint4 uu; short8 s; } af;
      af.uu.x = pkbf(p[0], p[1]); af.uu.y = pkbf(p[2], p[3]);
      af.uu.z = pkbf(p[4], p[5]); af.uu.w = pkbf(p[6], p[7]);
      o[mt][0] = MFMA16(af.s, vf0, o[mt][0]);
      o[mt][1] = MFMA16(af.s, vf1, o[mt][1]);
      o[mt][2] = MFMA16(af.s, vf2, o[mt][2]);
      o[mt][3] = MFMA16(af.s, vf3, o[mt][3]);
      lsumC[mt] = MFMA16(af.s, ones, lsumC[mt]);   // denominator, C-layout
    }
    __builtin_amdgcn_s_setprio(0);

    bu = bn;
  }
  #undef STAGE

  // ---- merge partial O / lsum across key-halves (via LDS) ----
  __syncthreads();
  {
    float* base = (float*)(smem + qh*12288);
    if (kh){
      #pragma unroll
      for (int mt = 0; mt < 4; ++mt){
        *(f32x4*)(base + (mt*2+0)*256 + lane*4) = o[mt][0];
        *(f32x4*)(base + (mt*2+1)*256 + lane*4) = o[mt][1];
        *(f32x4*)(base + (8+mt)*256 + lane*4)   = lsumC[mt];
      }
    }
  }
  __syncthreads();
  if (!kh){
    float* base = (float*)(smem + qh*12288);
    #pragma unroll
    for (int mt = 0; mt < 4; ++mt){
      o[mt][0] += *(const f32x4*)(base + (mt*2+0)*256 + lane*4);
      o[mt][1] += *(const f32x4*)(base + (mt*2+1)*256 + lane*4);
      lsumC[mt] += *(const f32x4*)(base + (8+mt)*256 + lane*4);
    }
  }
  __syncthreads();
  {
    float* base2 = (float*)(smem + qh*8192);
    if (kh){
      #pragma unroll
      for (int mt = 0; mt < 4; ++mt){
        *(f32x4*)(base2 + (mt*2+0)*256 + lane*4) = o[mt][2];
        *(f32x4*)(base2 + (mt*2+1)*256 + lane*4) = o[mt][3];
      }
    }
  }
  __syncthreads();
  if (!kh){
    float* base2 = (float*)(smem + qh*8192);
    #pragma unroll
    for (int mt = 0; mt < 4; ++mt){
      o[mt][2] += *(const f32x4*)(base2 + (mt*2+0)*256 + lane*4);
      o[mt][3] += *(const f32x4*)(base2 + (mt*2+1)*256 + lane*4);
    }
    // ---- epilogue: normalize + store bf16 r into this window's qpkt ----
    const float gm = gamma[0];
    ushort_t* rb = qpkt + (size_t)win*8192 + (size_t)qh*4096;
    #pragma unroll
    for (int mt = 0; mt < 4; ++mt){
      #pragma unroll
      for (int r = 0; r < 4; ++r){
        const float wg = gm * RCP(lsumC[mt][r]);   // den already per-lane (C-layout)
        const int qs = 16*mt + 4*h + r;
        #pragma unroll
        for (int u = 0; u < 4; ++u)
          rb[(size_t)qs*64 + 16*u + l15] = f2bf(wg * o[mt][u][r]);
      }
    }
  }
}

// ---------------------------------------------------------------------------
// Kernel 3: out = xref + r. LDS-tiled, both sides coalesced (R4-proven).
// ---------------------------------------------------------------------------
__global__ __launch_bounds__(256) void ep_kernel(
    const float* __restrict__ xref, const ushort_t* __restrict__ rbuf,
    float* __restrict__ out)
{
  __shared__ float tile[64][65];
  const int tid = threadIdx.x;
  const int bidx = blockIdx.x;                 // 2048 = b(2) x y(256) x xc(4)
  const int xc = bidx & 3, y = (bidx >> 2) & 255, b = bidx >> 10;
  const int wy = (y*745) >> 13, qy = y - wy*11;
  {
    const int ch = tid & 63, xs4 = tid >> 6;
    #pragma unroll
    for (int xi = 0; xi < 16; ++xi){
      const int xl = xi*4 + xs4;
      const int x = xc*64 + xl;
      const int wx = (x*745) >> 13, qx = x - wx*11;
      const size_t ridx = (size_t)(b*576 + wy*24 + wx)*8192 + (size_t)(qy*11 + qx)*64 + ch;
      tile[xl][ch] = __uint_as_float(((uint32)rbuf[ridx]) << 16);
    }
  }
  __syncthreads();
  {
    const int xl = tid & 63, cg = tid >> 6;
    const size_t base = (size_t)b*4194304 + (size_t)y*256 + xc*64 + xl;
    #pragma unroll
    for (int ci = 0; ci < 16; ++ci){
      const int c2 = ci*4 + cg;
      const size_t idx = base + (size_t)c2*65536;
      out[idx] = xref[idx] + tile[xl][c2];
    }
  }
}

// ---------------------------------------------------------------------------
extern "C" void kernel_launch(void* const* d_in, const int* in_sizes, int n_in,
                              void* d_out, int out_size, void* d_ws, size_t ws_size,
                              hipStream_t stream)
{
  const float* xk = (const float*)d_in[0];
  const float* xr = (const float*)d_in[1];
  const float* Wq = (const float*)d_in[2];
  const float* Wk = (const float*)d_in[3];
  const float* Wv = (const float*)d_in[4];
  const float* gm = (const float*)d_in[5];
  float* out = (float*)d_out;
  char* ws = (char*)d_ws;
  ushort_t* qp = (ushort_t*)(ws + QPKT_OFF);   // rbuf overlays this region
  ushort_t* kp = (ushort_t*)(ws + KPKT_OFF);
  ushort_t* vp = (ushort_t*)(ws + VPKT_OFF);
  (void)in_sizes; (void)n_in; (void)out_size; (void)ws_size;  // needs 56.6 MiB

  proj_kernel<<<2304, 256, 0, stream>>>(xk, xr, Wq, Wk, Wv, qp, kp, vp);
  attn_kernel<<<1152, 256, 0, stream>>>(qp, kp, vp, gm);
  ep_kernel<<<2048, 256, 0, stream>>>(xr, qp, out);
}